// Round 3
// baseline (422.982 us; speedup 1.0000x reference)
//
#include <hip/hip_runtime.h>
#include <hip/hip_bf16.h>

#define B_   8
#define N_   2048
#define FIN_ 64
#define H_   4
#define D_   32
#define HD_  128
#define ALPHA_ 0.2f
#define TI 16
#define CJ 64

// workspace layout (fp32 elements)
#define WH_OFF  0
#define SRC_OFF (B_*N_*HD_)              // 2,097,152
#define DST_OFF (SRC_OFF + B_*H_*N_)     // +65,536  (total ~8.9 MB)

// ---------------- prep: Wh = h@W (fp32), src/dst = Wh . a1/a2 ----------------
__global__ __launch_bounds__(128) void gat_prep(
    const float* __restrict__ h,
    const float* __restrict__ W,
    const float* __restrict__ a,
    float* __restrict__ Wh, float* __restrict__ src, float* __restrict__ dst)
{
    int row = blockIdx.x;              // b*N + n
    int b = row >> 11, n = row & (N_ - 1);
    __shared__ float hs[FIN_];
    int tid = threadIdx.x;
    if (tid < FIN_) hs[tid] = h[row * FIN_ + tid];
    __syncthreads();
    float acc = 0.f;
    #pragma unroll
    for (int k = 0; k < FIN_; ++k)
        acc += hs[k] * W[k * HD_ + tid];
    Wh[row * HD_ + tid] = acc;
    int hh = tid >> 5, d = tid & 31;
    float s1 = acc * a[hh * 64 + d];        // a[h, :D]
    float s2 = acc * a[hh * 64 + 32 + d];   // a[h, D:]
    #pragma unroll
    for (int off = 16; off >= 1; off >>= 1) {
        s1 += __shfl_xor(s1, off, 32);
        s2 += __shfl_xor(s2, off, 32);
    }
    if (d == 0) {
        src[(b * H_ + hh) * N_ + n] = s1;
        dst[(b * H_ + hh) * N_ + n] = s2;
    }
}

// ---------------- main: masked softmax + PV, fused, all heads ----------------
__global__ __launch_bounds__(256) void gat_main(
    const int*   __restrict__ adj,
    const float* __restrict__ Wh,
    const float* __restrict__ src,
    const float* __restrict__ dst,
    float* __restrict__ out)
{
    __shared__ __align__(16) float whs[CJ][HD_ + 4];    // +4 pad
    __shared__ __align__(16) float wls[H_][CJ][TI + 4]; // weights, i-contiguous, +4 pad
    __shared__ __align__(16) int   adjs[TI][CJ];
    __shared__ __align__(16) float dsts[H_][CJ];
    __shared__ __align__(16) float wsum[TI][H_];

    int bx = blockIdx.x;
    int b = bx >> 7;                 // 128 i-tiles per batch
    int i0 = (bx & 127) * TI;
    int tid = threadIdx.x;

    // --- weight-compute mapping: (i, h, jlane) ---
    int wi = tid >> 4;               // 0..15
    int wh = (tid >> 2) & 3;         // head
    int wj = tid & 3;                // j stride-4 lane
    float src_r = src[(b * H_ + wh) * N_ + i0 + wi];
    float wsum_r = 0.f;

    // --- accumulate mapping: tile = (it, head, dtile) x jgroup ---
    int jg   = tid & 7;              // j stride-8 group
    int tile = tid >> 3;             // 0..31
    int it   = tile >> 4;            // 0..1  (8-row half)
    int ht   = tile & 15;
    int ah   = ht >> 2;              // head
    int dt   = (ht & 3) * 8;         // d offset within head

    float acc[8][8];
    #pragma unroll
    for (int r = 0; r < 8; ++r)
        #pragma unroll
        for (int c = 0; c < 8; ++c) acc[r][c] = 0.f;

    const float* WhB  = Wh  + (size_t)b * N_ * HD_;
    const int*   adjB = adj + (size_t)b * N_ * N_ + (size_t)i0 * N_;

    for (int jc = 0; jc < N_; jc += CJ) {
        __syncthreads();
        // stage Wh chunk: 64 x 128 fp32, float4-coalesced
        #pragma unroll
        for (int t = 0; t < 8; ++t) {
            int idx = t * 256 + tid;          // float4 index
            int r = idx >> 5;
            int c4 = (idx & 31) << 2;
            *(float4*)&whs[r][c4] = *(const float4*)&WhB[(jc + r) * HD_ + c4];
        }
        // stage adj chunk: 16 x 64 ints
        #pragma unroll
        for (int t = 0; t < 4; ++t) {
            int idx = t * 256 + tid;
            adjs[idx >> 6][idx & 63] = adjB[(idx >> 6) * N_ + jc + (idx & 63)];
        }
        // stage dst chunk: 4 x 64
        dsts[tid >> 6][tid & 63] = dst[(b * H_ + (tid >> 6)) * N_ + jc + (tid & 63)];
        __syncthreads();

        // unnormalized weights: w = adj ? exp(lrelu(src_i + dst_j)) : 0
        #pragma unroll
        for (int t = 0; t < 16; ++t) {
            int j = wj + (t << 2);
            float e = src_r + dsts[wh][j];
            e = fmaxf(e, ALPHA_ * e);                 // leakyrelu
            e = fminf(e, 30.f);                       // inf guard (inactive for sane inputs)
            float w = adjs[wi][j] ? __expf(e) : 0.f;
            wls[wh][j][wi] = w;
            wsum_r += w;
        }
        __syncthreads();

        // register-tiled outer product: this thread: 8 i x 8 d, j = jg mod 8
        #pragma unroll
        for (int t = 0; t < 8; ++t) {
            int j = jg + (t << 3);
            float4 w0 = *(const float4*)&wls[ah][j][it * 8];
            float4 w1 = *(const float4*)&wls[ah][j][it * 8 + 4];
            float4 v0 = *(const float4*)&whs[j][ah * 32 + dt];
            float4 v1 = *(const float4*)&whs[j][ah * 32 + dt + 4];
            float wv[8] = {w0.x, w0.y, w0.z, w0.w, w1.x, w1.y, w1.z, w1.w};
            float vv[8] = {v0.x, v0.y, v0.z, v0.w, v1.x, v1.y, v1.z, v1.w};
            #pragma unroll
            for (int r = 0; r < 8; ++r)
                #pragma unroll
                for (int c = 0; c < 8; ++c)
                    acc[r][c] += wv[r] * vv[c];
        }
    }

    // reduce wsum over the 4 jlanes (consecutive lanes, width 4)
    wsum_r += __shfl_xor(wsum_r, 1, 4);
    wsum_r += __shfl_xor(wsum_r, 2, 4);
    if (wj == 0) wsum[wi][wh] = wsum_r;
    __syncthreads();

    // reduce acc over the 8 jgroups (consecutive lanes, width 8)
    #pragma unroll
    for (int r = 0; r < 8; ++r)
        #pragma unroll
        for (int c = 0; c < 8; ++c) {
            float v = acc[r][c];
            v += __shfl_xor(v, 1, 8);
            v += __shfl_xor(v, 2, 8);
            v += __shfl_xor(v, 4, 8);
            acc[r][c] = v;
        }

    if (jg == 0) {
        #pragma unroll
        for (int r = 0; r < 8; ++r) {
            int i = i0 + it * 8 + r;
            float inv = 1.f / wsum[it * 8 + r][ah];
            float4 o0, o1;
            o0.x = acc[r][0] * inv; o0.y = acc[r][1] * inv;
            o0.z = acc[r][2] * inv; o0.w = acc[r][3] * inv;
            o1.x = acc[r][4] * inv; o1.y = acc[r][5] * inv;
            o1.z = acc[r][6] * inv; o1.w = acc[r][7] * inv;
            float* po = &out[((size_t)b * N_ + i) * HD_ + ah * 32 + dt];
            *(float4*)po       = o0;
            *(float4*)(po + 4) = o1;
        }
    }
}

extern "C" void kernel_launch(void* const* d_in, const int* in_sizes, int n_in,
                              void* d_out, int out_size, void* d_ws, size_t ws_size,
                              hipStream_t stream) {
    const float* h   = (const float*)d_in[0];
    const int*   adj = (const int*)d_in[1];
    const float* W   = (const float*)d_in[2];
    const float* a   = (const float*)d_in[3];
    float* out = (float*)d_out;

    float* ws  = (float*)d_ws;
    float* Wh  = ws + WH_OFF;
    float* src = ws + SRC_OFF;
    float* dst = ws + DST_OFF;

    gat_prep<<<B_ * N_, 128, 0, stream>>>(h, W, a, Wh, src, dst);
    gat_main<<<B_ * (N_ / TI), 256, 0, stream>>>(adj, Wh, src, dst, out);
}

// Round 5
// 280.966 us; speedup vs baseline: 1.5055x; 1.5055x over previous
//
#include <hip/hip_runtime.h>
#include <hip/hip_bf16.h>

typedef short short8 __attribute__((ext_vector_type(8)));
typedef float floatx4 __attribute__((ext_vector_type(4)));

#define B_   8
#define N_   2048
#define FIN_ 64
#define H_   4
#define D_   32
#define HD_  128
#define ALPHA_ 0.2f

// ws layout (bytes):
//   WhT  bf16 [B][H][32][N]  @ 0        (4 MB)   d-major, for MFMA B-fragments
//   src  fp32 [B][H][N]      @ 4 MB     (256 KB)
//   dstb bf16 [B][H][N]      @ 4.25 MB  (128 KB)

__device__ __forceinline__ unsigned pk2bf(float x, float y) {   // RNE pack
    unsigned ux = __builtin_bit_cast(unsigned, x);
    ux = (ux + 0x7fffu + ((ux >> 16) & 1u)) >> 16;
    unsigned uy = __builtin_bit_cast(unsigned, y);
    uy = (uy + 0x7fffu + ((uy >> 16) & 1u)) >> 16;
    return ux | (uy << 16);
}

// ---------------- prep: Wh = h@W; WhT bf16 (d-major), src/dst projections ----
__global__ __launch_bounds__(256) void gat_prep2(
    const float* __restrict__ h, const float* __restrict__ W, const float* __restrict__ a,
    unsigned short* __restrict__ WhT, float* __restrict__ src, unsigned short* __restrict__ dstb)
{
    __shared__ float Ws[FIN_][HD_];     // 32 KB, staged once per block
    __shared__ float hsT[FIN_][36];     // h-tile transposed (k-major), padded
    int bx = blockIdx.x;
    int b = bx >> 6;
    int n0 = (bx & 63) * 32;            // 32 rows per block
    int tid = threadIdx.x;

    #pragma unroll
    for (int it = 0; it < 8; ++it) {    // W: 8192 floats as float4
        int idx = it * 256 + tid;
        int k = idx >> 5, c4 = (idx & 31) << 2;
        *(float4*)&Ws[k][c4] = *(const float4*)&W[k * HD_ + c4];
    }
    #pragma unroll
    for (int it = 0; it < 8; ++it) {    // h tile: 32x64, transposed into LDS
        int idx = it * 256 + tid;
        int r = idx >> 6, k = idx & 63;
        hsT[k][r] = h[((size_t)b * N_ + n0 + r) * FIN_ + k];
    }
    __syncthreads();

    int c = tid & 127;                  // output column = h*32+d
    int rq = tid >> 7;                  // 16-row half
    float acc[16];
    #pragma unroll
    for (int r = 0; r < 16; ++r) acc[r] = 0.f;
    for (int k = 0; k < FIN_; ++k) {
        float wv = Ws[k][c];            // 2-way LDS alias: free
        float4 h0 = *(const float4*)&hsT[k][rq * 16];
        float4 h1 = *(const float4*)&hsT[k][rq * 16 + 4];
        float4 h2 = *(const float4*)&hsT[k][rq * 16 + 8];
        float4 h3 = *(const float4*)&hsT[k][rq * 16 + 12];
        acc[0]  += h0.x * wv; acc[1]  += h0.y * wv; acc[2]  += h0.z * wv; acc[3]  += h0.w * wv;
        acc[4]  += h1.x * wv; acc[5]  += h1.y * wv; acc[6]  += h1.z * wv; acc[7]  += h1.w * wv;
        acc[8]  += h2.x * wv; acc[9]  += h2.y * wv; acc[10] += h2.z * wv; acc[11] += h2.w * wv;
        acc[12] += h3.x * wv; acc[13] += h3.y * wv; acc[14] += h3.z * wv; acc[15] += h3.w * wv;
    }

    // WhT write: row (b*128 + c), 16 consecutive n as bf16 (32 B)
    __attribute__((aligned(16))) unsigned pk[8];
    #pragma unroll
    for (int q = 0; q < 8; ++q) pk[q] = pk2bf(acc[2 * q], acc[2 * q + 1]);
    unsigned short* wrow = WhT + ((size_t)b * HD_ + c) * N_ + n0 + rq * 16;
    *(uint4*)wrow       = *(uint4*)&pk[0];
    *(uint4*)(wrow + 8) = *(uint4*)&pk[4];

    // src/dst: reduce over d (32 lanes per head within wave)
    int hh = c >> 5, d = c & 31;
    float a1v = a[hh * 64 + d];
    float a2v = a[hh * 64 + 32 + d];
    #pragma unroll
    for (int r = 0; r < 16; ++r) {
        float s1 = acc[r] * a1v;
        float s2 = acc[r] * a2v;
        #pragma unroll
        for (int off = 16; off >= 1; off >>= 1) {
            s1 += __shfl_xor(s1, off, 32);
            s2 += __shfl_xor(s2, off, 32);
        }
        if (d == 0) {
            int n = n0 + rq * 16 + r;
            src[(b * H_ + hh) * N_ + n] = s1;
            unsigned u = __builtin_bit_cast(unsigned, s2);
            u = (u + 0x7fffu + ((u >> 16) & 1u)) >> 16;
            dstb[(b * H_ + hh) * N_ + n] = (unsigned short)u;
        }
    }
}

// ---------------- main: per-wave head, MFMA PV, barrier-free K-loop ----------
__global__ __launch_bounds__(256) void gat_main2(
    const int* __restrict__ adj, const unsigned short* __restrict__ WhT,
    const float* __restrict__ src, const unsigned short* __restrict__ dstb,
    float* __restrict__ out)
{
    __shared__ unsigned short dsts[H_ * N_];   // 16 KB, staged once
    __shared__ float wsumS[H_][16];

    int bx = blockIdx.x;
    int b = bx >> 7;
    int i0 = (bx & 127) * 16;
    int tid = threadIdx.x;

    #pragma unroll
    for (int it = 0; it < 4; ++it) {           // 8192 ushorts = 1024 uint4s
        int idx = it * 256 + tid;
        *(uint4*)&dsts[idx * 8] = *(const uint4*)&dstb[(size_t)b * H_ * N_ + idx * 8];
    }

    int h = tid >> 6, l = tid & 63, g = l >> 4, m = l & 15;
    float src_r = src[(b * H_ + h) * N_ + i0 + m];
    const int* adjR = adj + ((size_t)b * N_ + i0 + m) * N_;          // this lane's i-row
    const unsigned short* WhR0 = WhT + ((size_t)(b * H_ + h) * 32 + m) * N_;
    const unsigned short* WhR1 = WhR0 + (size_t)16 * N_;
    const unsigned short* dstH = &dsts[h * N_];

    floatx4 acc0 = {0.f, 0.f, 0.f, 0.f}, acc1 = {0.f, 0.f, 0.f, 0.f};
    float wsum_r = 0.f;
    __syncthreads();

    for (int jc = 0; jc < N_; jc += 64) {
        #pragma unroll
        for (int k2 = 0; k2 < 2; ++k2) {
            int j0 = jc + k2 * 32 + g * 8;     // A-frag: k = g*8 + e within K=32 window
            int4 ad0 = *(const int4*)&adjR[j0];
            int4 ad1 = *(const int4*)&adjR[j0 + 4];
            uint4 dv = *(const uint4*)&dstH[j0];      // broadcast LDS read (16 lanes/addr)
            short8 bf0 = *(const short8*)&WhR0[j0];   // B-frag: n = m, k ascending
            short8 bf1 = *(const short8*)&WhR1[j0];
            const unsigned* du = (const unsigned*)&dv;
            const int* adp0 = (const int*)&ad0;
            const int* adp1 = (const int*)&ad1;
            float w[8];
            #pragma unroll
            for (int c2 = 0; c2 < 4; ++c2) {
                float dlo = __builtin_bit_cast(float, du[c2] << 16);
                float dhi = __builtin_bit_cast(float, du[c2] & 0xffff0000u);
                float e0 = src_r + dlo;
                float e1 = src_r + dhi;
                e0 = fminf(fmaxf(e0, ALPHA_ * e0), 30.f);   // leakyrelu + inf guard
                e1 = fminf(fmaxf(e1, ALPHA_ * e1), 30.f);
                int msk0 = (c2 < 2) ? adp0[2 * c2]     : adp1[2 * c2 - 4];
                int msk1 = (c2 < 2) ? adp0[2 * c2 + 1] : adp1[2 * c2 - 3];
                float w0 = msk0 ? __expf(e0) : 0.f;
                float w1 = msk1 ? __expf(e1) : 0.f;
                w[2 * c2]     = w0;
                w[2 * c2 + 1] = w1;
                wsum_r += w0 + w1;
            }
            union { unsigned u[4]; short8 s; } U;
            #pragma unroll
            for (int q = 0; q < 4; ++q) U.u[q] = pk2bf(w[2 * q], w[2 * q + 1]);
            short8 af = U.s;
            acc0 = __builtin_amdgcn_mfma_f32_16x16x32_bf16(af, bf0, acc0, 0, 0, 0);
            acc1 = __builtin_amdgcn_mfma_f32_16x16x32_bf16(af, bf1, acc1, 0, 0, 0);
        }
    }

    // full row-sum: combine the 4 k-groups (lanes m, m+16, m+32, m+48)
    wsum_r += __shfl_xor(wsum_r, 16);
    wsum_r += __shfl_xor(wsum_r, 32);
    if (g == 0) wsumS[h][m] = wsum_r;
    __syncthreads();

    // C/D: col = m, row = g*4 + reg (m89-verified)
    #pragma unroll
    for (int r = 0; r < 4; ++r) {
        float inv = 1.f / wsumS[h][g * 4 + r];
        size_t o = ((size_t)b * N_ + i0 + g * 4 + r) * HD_ + h * 32 + m;
        out[o]      = acc0[r] * inv;
        out[o + 16] = acc1[r] * inv;
    }
}

extern "C" void kernel_launch(void* const* d_in, const int* in_sizes, int n_in,
                              void* d_out, int out_size, void* d_ws, size_t ws_size,
                              hipStream_t stream) {
    const float* h   = (const float*)d_in[0];
    const int*   adj = (const int*)d_in[1];
    const float* W   = (const float*)d_in[2];
    const float* a   = (const float*)d_in[3];
    float* out = (float*)d_out;

    unsigned short* WhT  = (unsigned short*)d_ws;
    float*          src  = (float*)((char*)d_ws + 4u * 1024 * 1024);
    unsigned short* dstb = (unsigned short*)((char*)d_ws + 4u * 1024 * 1024 + 256u * 1024);

    gat_prep2<<<B_ * (N_ / 32), 256, 0, stream>>>(h, W, a, WhT, src, dstb);
    gat_main2<<<B_ * (N_ / 16), 256, 0, stream>>>(adj, WhT, src, dstb, out);
}

// Round 6
// 271.361 us; speedup vs baseline: 1.5587x; 1.0354x over previous
//
#include <hip/hip_runtime.h>
#include <hip/hip_bf16.h>

typedef short short8 __attribute__((ext_vector_type(8)));
typedef float floatx4 __attribute__((ext_vector_type(4)));

#define B_   8
#define N_   2048
#define FIN_ 64
#define H_   4
#define D_   32
#define HD_  128
#define ALPHA_ 0.2f
#define LOG2E_ 1.4426950408889634f

// ws layout (bytes):
//   packed adj bits [B][N][64]u32 @ 0        (4 MB)
//   WhT  bf16 [B][H][32][N]       @ 4 MB     (4 MB)   d-major, MFMA B-frags
//   src  fp32 [B][H][N] (×log2e)  @ 8 MB     (256 KB)
//   dstb bf16 [B][H][N] (×log2e)  @ 8.25 MB  (128 KB)

__device__ __forceinline__ float fexp2(float x) {      // exp2 via HW transcendental
#if __has_builtin(__builtin_amdgcn_exp2f)
    return __builtin_amdgcn_exp2f(x);
#else
    float r; asm("v_exp_f32 %0, %1" : "=v"(r) : "v"(x)); return r;
#endif
}

__device__ __forceinline__ unsigned pk2bf(float x, float y) {   // RNE pack
#if __has_builtin(__builtin_amdgcn_cvt_pk_bf16_f32)
    auto p = __builtin_amdgcn_cvt_pk_bf16_f32(x, y);
    return __builtin_bit_cast(unsigned, p);
#else
    unsigned ux = __builtin_bit_cast(unsigned, x);
    ux = (ux + 0x7fffu + ((ux >> 16) & 1u)) >> 16;
    unsigned uy = __builtin_bit_cast(unsigned, y);
    uy = (uy + 0x7fffu + ((uy >> 16) & 1u)) >> 16;
    return ux | (uy << 16);
#endif
}

// ---------------- pack: adj int32 {0,1} -> bitmask, 32x less traffic ---------
__global__ __launch_bounds__(256) void pack_adj(
    const int* __restrict__ adj, unsigned* __restrict__ packed)
{
    size_t gw = (size_t)blockIdx.x * 256 + threadIdx.x;   // word index
    const int4* p = (const int4*)(adj + gw * 32);
    unsigned w = 0;
    #pragma unroll
    for (int t = 0; t < 8; ++t) {
        int4 v = p[t];
        w |= ((unsigned)v.x << (4 * t))     | ((unsigned)v.y << (4 * t + 1)) |
             ((unsigned)v.z << (4 * t + 2)) | ((unsigned)v.w << (4 * t + 3));
    }
    packed[gw] = w;
}

// ---------------- prep: Wh = h@W; WhT bf16 (d-major), src/dst (x log2e) ------
__global__ __launch_bounds__(256) void gat_prep2(
    const float* __restrict__ h, const float* __restrict__ W, const float* __restrict__ a,
    unsigned short* __restrict__ WhT, float* __restrict__ src, unsigned short* __restrict__ dstb)
{
    __shared__ float Ws[FIN_][HD_];
    __shared__ float hsT[FIN_][36];
    int bx = blockIdx.x;
    int b = bx >> 6;
    int n0 = (bx & 63) * 32;
    int tid = threadIdx.x;

    #pragma unroll
    for (int it = 0; it < 8; ++it) {
        int idx = it * 256 + tid;
        int k = idx >> 5, c4 = (idx & 31) << 2;
        *(float4*)&Ws[k][c4] = *(const float4*)&W[k * HD_ + c4];
    }
    #pragma unroll
    for (int it = 0; it < 8; ++it) {
        int idx = it * 256 + tid;
        int r = idx >> 6, k = idx & 63;
        hsT[k][r] = h[((size_t)b * N_ + n0 + r) * FIN_ + k];
    }
    __syncthreads();

    int c = tid & 127;
    int rq = tid >> 7;
    float acc[16];
    #pragma unroll
    for (int r = 0; r < 16; ++r) acc[r] = 0.f;
    for (int k = 0; k < FIN_; ++k) {
        float wv = Ws[k][c];
        float4 h0 = *(const float4*)&hsT[k][rq * 16];
        float4 h1 = *(const float4*)&hsT[k][rq * 16 + 4];
        float4 h2 = *(const float4*)&hsT[k][rq * 16 + 8];
        float4 h3 = *(const float4*)&hsT[k][rq * 16 + 12];
        acc[0]  += h0.x * wv; acc[1]  += h0.y * wv; acc[2]  += h0.z * wv; acc[3]  += h0.w * wv;
        acc[4]  += h1.x * wv; acc[5]  += h1.y * wv; acc[6]  += h1.z * wv; acc[7]  += h1.w * wv;
        acc[8]  += h2.x * wv; acc[9]  += h2.y * wv; acc[10] += h2.z * wv; acc[11] += h2.w * wv;
        acc[12] += h3.x * wv; acc[13] += h3.y * wv; acc[14] += h3.z * wv; acc[15] += h3.w * wv;
    }

    __attribute__((aligned(16))) unsigned pk[8];
    #pragma unroll
    for (int q = 0; q < 8; ++q) pk[q] = pk2bf(acc[2 * q], acc[2 * q + 1]);
    unsigned short* wrow = WhT + ((size_t)b * HD_ + c) * N_ + n0 + rq * 16;
    *(uint4*)wrow       = *(uint4*)&pk[0];
    *(uint4*)(wrow + 8) = *(uint4*)&pk[4];

    int hh = c >> 5, d = c & 31;
    float a1v = a[hh * 64 + d];
    float a2v = a[hh * 64 + 32 + d];
    #pragma unroll
    for (int r = 0; r < 16; ++r) {
        float s1 = acc[r] * a1v;
        float s2 = acc[r] * a2v;
        #pragma unroll
        for (int off = 16; off >= 1; off >>= 1) {
            s1 += __shfl_xor(s1, off, 32);
            s2 += __shfl_xor(s2, off, 32);
        }
        if (d == 0) {
            int n = n0 + rq * 16 + r;
            src[(b * H_ + hh) * N_ + n] = s1 * LOG2E_;      // pre-scaled for exp2
            unsigned u = __builtin_bit_cast(unsigned, s2 * LOG2E_);
            u = (u + 0x7fffu + ((u >> 16) & 1u)) >> 16;
            dstb[(b * H_ + hh) * N_ + n] = (unsigned short)u;
        }
    }
}

// ---------------- main: LDS adj bits, MFMA PV + MFMA row-sum -----------------
__global__ __launch_bounds__(256) void gat_main3(
    const unsigned* __restrict__ packed, const unsigned short* __restrict__ WhT,
    const float* __restrict__ src, const unsigned short* __restrict__ dstb,
    float* __restrict__ out)
{
    __shared__ unsigned short dsts[H_ * N_];   // 16 KB
    __shared__ unsigned adjW[16][68];          // 4.4 KB, stride 68: conflict-free

    int bx = blockIdx.x;
    int b = bx >> 7;
    int i0 = (bx & 127) * 16;
    int tid = threadIdx.x;

    #pragma unroll
    for (int it = 0; it < 4; ++it) {           // dst: 8192 ushorts = 1024 uint4
        int idx = it * 256 + tid;
        *(uint4*)&dsts[idx * 8] = *(const uint4*)&dstb[(size_t)b * H_ * N_ + idx * 8];
    }
    {                                          // adj bits: 16 rows x 64 words
        int row = tid >> 4, c4 = (tid & 15) * 4;
        *(int4*)&adjW[row][c4] =
            *(const int4*)&packed[((size_t)b * N_ + i0 + row) * 64 + c4];
    }

    int h = tid >> 6, l = tid & 63, g = l >> 4, m = l & 15;
    int g8 = g << 3;
    float src_r = src[(b * H_ + h) * N_ + i0 + m];
    const unsigned short* WhR0 = WhT + ((size_t)(b * H_ + h) * 32 + m) * N_;
    const unsigned short* WhR1 = WhR0 + (size_t)16 * N_;
    const unsigned short* dstH = &dsts[h * N_];

    short8 ones;
    #pragma unroll
    for (int q = 0; q < 8; ++q) ones[q] = (short)0x3F80;   // bf16 1.0

    floatx4 acc0 = {0.f, 0.f, 0.f, 0.f};
    floatx4 acc1 = {0.f, 0.f, 0.f, 0.f};
    floatx4 acc2 = {0.f, 0.f, 0.f, 0.f};       // row-sums via B=ones
    __syncthreads();

    for (int jc = 0; jc < N_; jc += 64) {
        #pragma unroll
        for (int k2 = 0; k2 < 2; ++k2) {
            int j0 = jc + (k2 << 5) + g8;
            unsigned word = adjW[m][(jc >> 5) + k2];   // broadcast + 2-way: free
            unsigned sh = word >> g8;                  // this lane's 8 mask bits
            uint4 dv = *(const uint4*)&dstH[j0];
            short8 bf0 = *(const short8*)&WhR0[j0];
            short8 bf1 = *(const short8*)&WhR1[j0];
            const unsigned* du = (const unsigned*)&dv;
            float wv[8];
            #pragma unroll
            for (int c2 = 0; c2 < 4; ++c2) {
                float dlo = __builtin_bit_cast(float, du[c2] << 16);
                float dhi = __builtin_bit_cast(float, du[c2] & 0xffff0000u);
                float e0 = src_r + dlo;
                float e1 = src_r + dhi;
                e0 = fmaxf(e0, ALPHA_ * e0);           // lrelu (log2e>0 commutes)
                e1 = fmaxf(e1, ALPHA_ * e1);
                float x0 = fexp2(e0);
                float x1 = fexp2(e1);
                wv[2 * c2]     = (sh & (1u << (2 * c2))) ? x0 : 0.f;
                wv[2 * c2 + 1] = (sh & (2u << (2 * c2))) ? x1 : 0.f;
            }
            union { unsigned u[4]; short8 s; } U;
            #pragma unroll
            for (int q = 0; q < 4; ++q) U.u[q] = pk2bf(wv[2 * q], wv[2 * q + 1]);
            short8 af = U.s;
            acc0 = __builtin_amdgcn_mfma_f32_16x16x32_bf16(af, bf0, acc0, 0, 0, 0);
            acc1 = __builtin_amdgcn_mfma_f32_16x16x32_bf16(af, bf1, acc1, 0, 0, 0);
            acc2 = __builtin_amdgcn_mfma_f32_16x16x32_bf16(af, ones, acc2, 0, 0, 0);
        }
    }

    // C/D: col = m, row = g*4 + r; acc2[r] = wsum for that row (all cols equal)
    #pragma unroll
    for (int r = 0; r < 4; ++r) {
        float inv = __builtin_amdgcn_rcpf(acc2[r]);
        size_t o = ((size_t)b * N_ + i0 + g * 4 + r) * HD_ + h * 32 + m;
        out[o]      = acc0[r] * inv;
        out[o + 16] = acc1[r] * inv;
    }
}

extern "C" void kernel_launch(void* const* d_in, const int* in_sizes, int n_in,
                              void* d_out, int out_size, void* d_ws, size_t ws_size,
                              hipStream_t stream) {
    const float* h   = (const float*)d_in[0];
    const int*   adj = (const int*)d_in[1];
    const float* W   = (const float*)d_in[2];
    const float* a   = (const float*)d_in[3];
    float* out = (float*)d_out;

    unsigned*       packed = (unsigned*)d_ws;
    unsigned short* WhT    = (unsigned short*)((char*)d_ws + 4u * 1024 * 1024);
    float*          src    = (float*)((char*)d_ws + 8u * 1024 * 1024);
    unsigned short* dstb   = (unsigned short*)((char*)d_ws + 8u * 1024 * 1024 + 256u * 1024);

    pack_adj<<<(B_ * N_ * (N_ / 32)) / 256, 256, 0, stream>>>(adj, packed);
    gat_prep2<<<B_ * (N_ / 32), 256, 0, stream>>>(h, W, a, WhT, src, dstb);
    gat_main3<<<B_ * (N_ / 16), 256, 0, stream>>>(packed, WhT, src, dstb, out);
}